// Round 6
// baseline (1324.844 us; speedup 1.0000x reference)
//
#include <hip/hip_runtime.h>

#define B_  4
#define NN_ 20
#define C_  128
#define H_  8
#define W_  32
#define P_  256      // H*W
#define GS_ 32
#define L_  1024     // GS*GS
#define K_  5120     // NN*P

// ---------------- ws layout (float elements) ----------------
// ind   : int   [B*L*NN]   @ 0         (81920)
// Kscal : float [B*L*NN]   @ 81920     (81920)
// Rc    : float [360*P]    @ 163840    (92160)
// Pc    : float [B*NN*P]   @ 256000    (20480)
// pano  : float [B*NN*2*P] @ 276480    (40960)
// ovmax : float [B*L]      @ 317440    (4096)
// ovmean: float [B*L]      @ 321536    (4096)
// total 325632 floats = 1.24 MB

__global__ __launch_bounds__(256) void k_pano(const float* __restrict__ feats,
                                              float* __restrict__ pano) {
  int t = blockIdx.x * 256 + threadIdx.x;       // B*NN*P = 20480
  int p = t & 255, bn = t >> 8;
  const float* src = feats + bn * C_ * P_ + p;
  float mx = -3.4e38f, sm = 0.f;
  #pragma unroll 8
  for (int c = 0; c < C_; ++c) { float v = src[c * P_]; mx = fmaxf(mx, v); sm += v; }
  pano[(bn * 2 + 0) * P_ + p] = mx;
  pano[(bn * 2 + 1) * P_ + p] = sm * (1.0f / 128.0f);
}

__global__ __launch_bounds__(256) void k_ov(const float* __restrict__ over,
                                            float* __restrict__ ovmax,
                                            float* __restrict__ ovmean) {
  int t = blockIdx.x * 256 + threadIdx.x;       // B*L = 4096
  int b = t >> 10, l = t & 1023;
  const float* src = over + b * C_ * L_ + l;
  float mx = -3.4e38f, sm = 0.f;
  #pragma unroll 8
  for (int c = 0; c < C_; ++c) { float v = src[c * L_]; mx = fmaxf(mx, v); sm += v; }
  ovmax[t] = mx; ovmean[t] = sm * (1.0f / 128.0f);
}

// Rays conv: Rc[a,p] = fw0*conv3(rays[a], w1[1..3]) + fw1*conv5(rays[a], w2[1..3])
__global__ __launch_bounds__(256) void k_rc(const float* __restrict__ rays,
                                            const float* __restrict__ w1,
                                            const float* __restrict__ w2,
                                            const float* __restrict__ fw,
                                            float* __restrict__ Rc) {
  __shared__ float s[3 * P_];
  int a = blockIdx.x, tid = threadIdx.x;
  #pragma unroll
  for (int c = 0; c < 3; ++c) s[c * P_ + tid] = rays[(a * 3 + c) * P_ + tid];
  __syncthreads();
  int y = tid >> 5, x = tid & 31;
  float acc1 = 0.f, acc2 = 0.f;
  #pragma unroll
  for (int c = 0; c < 3; ++c) {
    const float* sc  = s + c * P_;
    const float* w1c = w1 + (1 + c) * 9;
    const float* w2c = w2 + (1 + c) * 25;
    #pragma unroll
    for (int dy = 0; dy < 3; ++dy) { int yy = ((y + dy + 7) & 7) * 32;
      #pragma unroll
      for (int dx = 0; dx < 3; ++dx) { int xx = (x + dx + 31) & 31;
        acc1 += sc[yy + xx] * w1c[dy * 3 + dx]; } }
    #pragma unroll
    for (int dy = 0; dy < 5; ++dy) { int yy = ((y + dy + 6) & 7) * 32;
      #pragma unroll
      for (int dx = 0; dx < 5; ++dx) { int xx = (x + dx + 30) & 31;
        acc2 += sc[yy + xx] * w2c[dy * 5 + dx]; } }
  }
  Rc[a * P_ + tid] = fw[0] * acc1 + fw[1] * acc2;
}

// Pano conv: Pc[bn,p] = fw0*conv3(pano, w1[4..5]) + fw1*conv5(pano, w2[4..5])
__global__ __launch_bounds__(256) void k_pc(const float* __restrict__ pano,
                                            const float* __restrict__ w1,
                                            const float* __restrict__ w2,
                                            const float* __restrict__ fw,
                                            float* __restrict__ Pc) {
  __shared__ float s[2 * P_];
  int bn = blockIdx.x, tid = threadIdx.x;
  s[tid]      = pano[(bn * 2 + 0) * P_ + tid];
  s[P_ + tid] = pano[(bn * 2 + 1) * P_ + tid];
  __syncthreads();
  int y = tid >> 5, x = tid & 31;
  float acc1 = 0.f, acc2 = 0.f;
  #pragma unroll
  for (int c = 0; c < 2; ++c) {
    const float* sc  = s + c * P_;
    const float* w1c = w1 + (4 + c) * 9;
    const float* w2c = w2 + (4 + c) * 25;
    #pragma unroll
    for (int dy = 0; dy < 3; ++dy) { int yy = ((y + dy + 7) & 7) * 32;
      #pragma unroll
      for (int dx = 0; dx < 3; ++dx) { int xx = (x + dx + 31) & 31;
        acc1 += sc[yy + xx] * w1c[dy * 3 + dx]; } }
    #pragma unroll
    for (int dy = 0; dy < 5; ++dy) { int yy = ((y + dy + 6) & 7) * 32;
      #pragma unroll
      for (int dx = 0; dx < 5; ++dx) { int xx = (x + dx + 30) & 31;
        acc2 += sc[yy + xx] * w2c[dy * 5 + dx]; } }
  }
  Pc[bn * P_ + tid] = fw[0] * acc1 + fw[1] * acc2;
}

// Per-(b,l,n): ray index + scalar (constant-channel) logit term
__global__ __launch_bounds__(256) void k_geo(const float* __restrict__ bbox,
                                             const float* __restrict__ locs,
                                             const float* __restrict__ ovmax,
                                             const float* __restrict__ ovmean,
                                             const float* __restrict__ w1,
                                             const float* __restrict__ w2,
                                             const float* __restrict__ b1,
                                             const float* __restrict__ b2,
                                             const float* __restrict__ fw,
                                             const float* __restrict__ fb,
                                             int* __restrict__ ind,
                                             float* __restrict__ Kscal) {
  int t = blockIdx.x * 256 + threadIdx.x;       // B*L*NN = 81920
  int n = t % NN_;
  int r = t / NN_;                              // b*L + l
  int l = r & 1023, b = r >> 10;
  int i = l >> 5, j = l & 31;
  float y0 = bbox[b * 4 + 0], x0 = bbox[b * 4 + 1];
  float y1 = bbox[b * 4 + 2], x1 = bbox[b * 4 + 3];
  float gy = (i == 31) ? y1 : (y0 + ((y1 - y0) / 31.0f) * (float)i);  // linspace endpoint
  float gx = (j == 31) ? x1 : (x0 + ((x1 - x0) / 31.0f) * (float)j);
  float d0 = gy - locs[(b * NN_ + n) * 2 + 0];
  float d1 = gx - locs[(b * NN_ + n) * 2 + 1];
  float D  = sqrtf(d0 * d0 + d1 * d1 + 1e-12f);
  float th = atan2f(d1, d0);
  if (th < 0.f) th += 6.283185307179586f;
  float deg = th * 57.29577951308232f;
  int di = (int)rintf(deg);                     // round-half-even, matches jnp.round
  if (di >= 360) di -= 360;
  float s10 = 0, s16 = 0, s17 = 0;
  #pragma unroll
  for (int q = 0; q < 9; ++q) { s10 += w1[q]; s16 += w1[54 + q]; s17 += w1[63 + q]; }
  float s20 = 0, s26 = 0, s27 = 0;
  #pragma unroll
  for (int q = 0; q < 25; ++q) { s20 += w2[q]; s26 += w2[150 + q]; s27 += w2[175 + q]; }
  float om = ovmax[r], oa = ovmean[r];
  ind[t]   = di;
  Kscal[t] = fw[0] * (D * s10 + om * s16 + oa * s17 + b1[0])
           + fw[1] * (D * s20 + om * s26 + oa * s27 + b2[0]) + fb[0];
}

// Per grid cell: assemble logits, softmax over (n,p)=5120, write fp32 attn.
__global__ __launch_bounds__(256) void k_soft(const float* __restrict__ Rc,
                                              const float* __restrict__ Pc,
                                              const float* __restrict__ Kscal,
                                              const int* __restrict__ ind,
                                              float* __restrict__ attn) {
  int bl = blockIdx.x;                           // b*L + l
  int b = bl >> 10;
  int tid = threadIdx.x;                         // pixel p
  __shared__ float sK[NN_];
  __shared__ int   sI[NN_];
  __shared__ float red[256];
  if (tid < NN_) { sI[tid] = ind[bl * NN_ + tid]; sK[tid] = Kscal[bl * NN_ + tid]; }
  __syncthreads();
  float lg[NN_];
  #pragma unroll
  for (int n = 0; n < NN_; ++n)
    lg[n] = Rc[sI[n] * P_ + tid] + Pc[(b * NN_ + n) * P_ + tid] + sK[n];
  float m = -3.4e38f;
  #pragma unroll
  for (int n = 0; n < NN_; ++n) m = fmaxf(m, lg[n]);
  red[tid] = m; __syncthreads();
  for (int s = 128; s > 0; s >>= 1) {
    if (tid < s) red[tid] = fmaxf(red[tid], red[tid + s]);
    __syncthreads();
  }
  m = red[0];
  __syncthreads();
  float ssum = 0.f;
  #pragma unroll
  for (int n = 0; n < NN_; ++n) { lg[n] = expf(lg[n] - m); ssum += lg[n]; }
  red[tid] = ssum; __syncthreads();
  for (int s = 128; s > 0; s >>= 1) {
    if (tid < s) red[tid] += red[tid + s];
    __syncthreads();
  }
  float inv = 1.0f / red[0];
  #pragma unroll
  for (int n = 0; n < NN_; ++n)
    attn[((size_t)bl * NN_ + n) * P_ + tid] = lg[n] * inv;
}

// gf[b,l,c] = sum_{n,p} attn[b,l,n,p] * feats[b,n,c,p]
// One block per (b,l); attn row staged in LDS; feats float4 loads.
__global__ __launch_bounds__(128) void k_agg(const float* __restrict__ attn,
                                             const float* __restrict__ feats,
                                             float* __restrict__ gf) {
  __shared__ float sA[K_];                       // 20 KB
  int bl = blockIdx.x;                           // b*L + l
  int b = bl >> 10;
  int c = threadIdx.x;                           // 0..127
  const float* wrow = attn + (size_t)bl * K_;
  for (int i = threadIdx.x; i < K_; i += 128) sA[i] = wrow[i];
  __syncthreads();
  const float* fbase = feats + (size_t)b * NN_ * C_ * P_;
  float acc = 0.f;
  for (int n = 0; n < NN_; ++n) {
    const float* fc = fbase + (n * C_ + c) * P_;
    const float* an = sA + n * P_;
    #pragma unroll 8
    for (int p = 0; p < P_; p += 4) {
      float4 v = *(const float4*)(fc + p);
      acc += v.x * an[p + 0] + v.y * an[p + 1] + v.z * an[p + 2] + v.w * an[p + 3];
    }
  }
  gf[(size_t)bl * C_ + c] = acc;
}

extern "C" void kernel_launch(void* const* d_in, const int* in_sizes, int n_in,
                              void* d_out, int out_size, void* d_ws, size_t ws_size,
                              hipStream_t stream) {
  const float* bbox  = (const float*)d_in[0];
  const float* locs  = (const float*)d_in[1];
  const float* feats = (const float*)d_in[2];
  const float* over  = (const float*)d_in[3];
  const float* rays  = (const float*)d_in[4];
  const float* w1    = (const float*)d_in[5];
  const float* b1    = (const float*)d_in[6];
  const float* w2    = (const float*)d_in[7];
  const float* b2    = (const float*)d_in[8];
  const float* fw    = (const float*)d_in[9];
  const float* fb    = (const float*)d_in[10];

  float* ws     = (float*)d_ws;
  int*   ind    = (int*)ws;
  float* Kscal  = ws + 81920;
  float* Rc     = ws + 163840;
  float* Pc     = ws + 256000;
  float* pano   = ws + 276480;
  float* ovmax  = ws + 317440;
  float* ovmean = ws + 321536;

  float* gf   = (float*)d_out;
  float* attn = gf + (B_ * L_ * C_);             // 524288 floats in, 20.97M floats
  
  k_pano<<<80, 256, 0, stream>>>(feats, pano);
  k_ov  <<<16, 256, 0, stream>>>(over, ovmax, ovmean);
  k_rc  <<<360, 256, 0, stream>>>(rays, w1, w2, fw, Rc);
  k_pc  <<<80, 256, 0, stream>>>(pano, w1, w2, fw, Pc);
  k_geo <<<320, 256, 0, stream>>>(bbox, locs, ovmax, ovmean, w1, w2, b1, b2, fw, fb,
                                  ind, Kscal);
  k_soft<<<4096, 256, 0, stream>>>(Rc, Pc, Kscal, ind, attn);
  k_agg <<<4096, 128, 0, stream>>>(attn, feats, gf);
}

// Round 7
// 525.247 us; speedup vs baseline: 2.5223x; 2.5223x over previous
//
#include <hip/hip_runtime.h>

#define B_  4
#define NN_ 20
#define C_  128
#define H_  8
#define W_  32
#define P_  256      // H*W
#define GS_ 32
#define L_  1024     // GS*GS
#define K_  5120     // NN*P

// ---------------- ws layout (float elements) ----------------
// ind   : int   [B*L*NN]   @ 0         (81920)
// Kscal : float [B*L*NN]   @ 81920     (81920)
// Rc    : float [360*P]    @ 163840    (92160)
// Pc    : float [B*NN*P]   @ 256000    (20480)
// pano  : float [B*NN*2*P] @ 276480    (40960)
// ovmax : float [B*L]      @ 317440    (4096)
// ovmean: float [B*L]      @ 321536    (4096)
// Ft    : float [B*K*C]    @ 325632    (2621440)  -> 11.79 MB total (R1 proved OK)

__global__ __launch_bounds__(256) void k_pano(const float* __restrict__ feats,
                                              float* __restrict__ pano) {
  int t = blockIdx.x * 256 + threadIdx.x;       // B*NN*P = 20480
  int p = t & 255, bn = t >> 8;
  const float* src = feats + bn * C_ * P_ + p;
  float mx = -3.4e38f, sm = 0.f;
  #pragma unroll 8
  for (int c = 0; c < C_; ++c) { float v = src[c * P_]; mx = fmaxf(mx, v); sm += v; }
  pano[(bn * 2 + 0) * P_ + p] = mx;
  pano[(bn * 2 + 1) * P_ + p] = sm * (1.0f / 128.0f);
}

__global__ __launch_bounds__(256) void k_ov(const float* __restrict__ over,
                                            float* __restrict__ ovmax,
                                            float* __restrict__ ovmean) {
  int t = blockIdx.x * 256 + threadIdx.x;       // B*L = 4096
  int b = t >> 10, l = t & 1023;
  const float* src = over + b * C_ * L_ + l;
  float mx = -3.4e38f, sm = 0.f;
  #pragma unroll 8
  for (int c = 0; c < C_; ++c) { float v = src[c * L_]; mx = fmaxf(mx, v); sm += v; }
  ovmax[t] = mx; ovmean[t] = sm * (1.0f / 128.0f);
}

// Rays conv: Rc[a,p] = fw0*conv3(rays[a], w1[1..3]) + fw1*conv5(rays[a], w2[1..3])
__global__ __launch_bounds__(256) void k_rc(const float* __restrict__ rays,
                                            const float* __restrict__ w1,
                                            const float* __restrict__ w2,
                                            const float* __restrict__ fw,
                                            float* __restrict__ Rc) {
  __shared__ float s[3 * P_];
  int a = blockIdx.x, tid = threadIdx.x;
  #pragma unroll
  for (int c = 0; c < 3; ++c) s[c * P_ + tid] = rays[(a * 3 + c) * P_ + tid];
  __syncthreads();
  int y = tid >> 5, x = tid & 31;
  float acc1 = 0.f, acc2 = 0.f;
  #pragma unroll
  for (int c = 0; c < 3; ++c) {
    const float* sc  = s + c * P_;
    const float* w1c = w1 + (1 + c) * 9;
    const float* w2c = w2 + (1 + c) * 25;
    #pragma unroll
    for (int dy = 0; dy < 3; ++dy) { int yy = ((y + dy + 7) & 7) * 32;
      #pragma unroll
      for (int dx = 0; dx < 3; ++dx) { int xx = (x + dx + 31) & 31;
        acc1 += sc[yy + xx] * w1c[dy * 3 + dx]; } }
    #pragma unroll
    for (int dy = 0; dy < 5; ++dy) { int yy = ((y + dy + 6) & 7) * 32;
      #pragma unroll
      for (int dx = 0; dx < 5; ++dx) { int xx = (x + dx + 30) & 31;
        acc2 += sc[yy + xx] * w2c[dy * 5 + dx]; } }
  }
  Rc[a * P_ + tid] = fw[0] * acc1 + fw[1] * acc2;
}

// Pano conv: Pc[bn,p] = fw0*conv3(pano, w1[4..5]) + fw1*conv5(pano, w2[4..5])
__global__ __launch_bounds__(256) void k_pc(const float* __restrict__ pano,
                                            const float* __restrict__ w1,
                                            const float* __restrict__ w2,
                                            const float* __restrict__ fw,
                                            float* __restrict__ Pc) {
  __shared__ float s[2 * P_];
  int bn = blockIdx.x, tid = threadIdx.x;
  s[tid]      = pano[(bn * 2 + 0) * P_ + tid];
  s[P_ + tid] = pano[(bn * 2 + 1) * P_ + tid];
  __syncthreads();
  int y = tid >> 5, x = tid & 31;
  float acc1 = 0.f, acc2 = 0.f;
  #pragma unroll
  for (int c = 0; c < 2; ++c) {
    const float* sc  = s + c * P_;
    const float* w1c = w1 + (4 + c) * 9;
    const float* w2c = w2 + (4 + c) * 25;
    #pragma unroll
    for (int dy = 0; dy < 3; ++dy) { int yy = ((y + dy + 7) & 7) * 32;
      #pragma unroll
      for (int dx = 0; dx < 3; ++dx) { int xx = (x + dx + 31) & 31;
        acc1 += sc[yy + xx] * w1c[dy * 3 + dx]; } }
    #pragma unroll
    for (int dy = 0; dy < 5; ++dy) { int yy = ((y + dy + 6) & 7) * 32;
      #pragma unroll
      for (int dx = 0; dx < 5; ++dx) { int xx = (x + dx + 30) & 31;
        acc2 += sc[yy + xx] * w2c[dy * 5 + dx]; } }
  }
  Pc[bn * P_ + tid] = fw[0] * acc1 + fw[1] * acc2;
}

// Per-(b,l,n): ray index + scalar (constant-channel) logit term
__global__ __launch_bounds__(256) void k_geo(const float* __restrict__ bbox,
                                             const float* __restrict__ locs,
                                             const float* __restrict__ ovmax,
                                             const float* __restrict__ ovmean,
                                             const float* __restrict__ w1,
                                             const float* __restrict__ w2,
                                             const float* __restrict__ b1,
                                             const float* __restrict__ b2,
                                             const float* __restrict__ fw,
                                             const float* __restrict__ fb,
                                             int* __restrict__ ind,
                                             float* __restrict__ Kscal) {
  int t = blockIdx.x * 256 + threadIdx.x;       // B*L*NN = 81920
  int n = t % NN_;
  int r = t / NN_;                              // b*L + l
  int l = r & 1023, b = r >> 10;
  int i = l >> 5, j = l & 31;
  float y0 = bbox[b * 4 + 0], x0 = bbox[b * 4 + 1];
  float y1 = bbox[b * 4 + 2], x1 = bbox[b * 4 + 3];
  float gy = (i == 31) ? y1 : (y0 + ((y1 - y0) / 31.0f) * (float)i);  // linspace endpoint
  float gx = (j == 31) ? x1 : (x0 + ((x1 - x0) / 31.0f) * (float)j);
  float d0 = gy - locs[(b * NN_ + n) * 2 + 0];
  float d1 = gx - locs[(b * NN_ + n) * 2 + 1];
  float D  = sqrtf(d0 * d0 + d1 * d1 + 1e-12f);
  float th = atan2f(d1, d0);
  if (th < 0.f) th += 6.283185307179586f;
  float deg = th * 57.29577951308232f;
  int di = (int)rintf(deg);                     // round-half-even, matches jnp.round
  if (di >= 360) di -= 360;
  float s10 = 0, s16 = 0, s17 = 0;
  #pragma unroll
  for (int q = 0; q < 9; ++q) { s10 += w1[q]; s16 += w1[54 + q]; s17 += w1[63 + q]; }
  float s20 = 0, s26 = 0, s27 = 0;
  #pragma unroll
  for (int q = 0; q < 25; ++q) { s20 += w2[q]; s26 += w2[150 + q]; s27 += w2[175 + q]; }
  float om = ovmax[r], oa = ovmean[r];
  ind[t]   = di;
  Kscal[t] = fw[0] * (D * s10 + om * s16 + oa * s17 + b1[0])
           + fw[1] * (D * s20 + om * s26 + oa * s27 + b2[0]) + fb[0];
}

// Transpose feats [b,n,c,p] -> Ft [b, k=(n,p), c]  (c contiguous)
__global__ __launch_bounds__(256) void k_ft(const float* __restrict__ feats,
                                            float* __restrict__ Ft) {
  __shared__ float s[32 * 257];
  int bn = blockIdx.x;                           // b*NN + n
  int b = bn / NN_, n = bn % NN_;
  int tid = threadIdx.x;
  for (int c0 = 0; c0 < C_; c0 += 32) {
    __syncthreads();
    #pragma unroll 4
    for (int cc = 0; cc < 32; ++cc)
      s[cc * 257 + tid] = feats[(bn * C_ + c0 + cc) * P_ + tid];
    __syncthreads();
    int c = tid & 31, p8 = tid >> 5;
    #pragma unroll 4
    for (int pp = 0; pp < 32; ++pp) {
      int p = pp * 8 + p8;
      Ft[((size_t)b * K_ + n * P_ + p) * C_ + c0 + c] = s[c * 257 + p];
    }
  }
}

// Per grid cell: assemble logits, softmax over (n,p)=5120, write fp32 attn.
__global__ __launch_bounds__(256) void k_soft(const float* __restrict__ Rc,
                                              const float* __restrict__ Pc,
                                              const float* __restrict__ Kscal,
                                              const int* __restrict__ ind,
                                              float* __restrict__ attn) {
  int bl = blockIdx.x;                           // b*L + l
  int b = bl >> 10;
  int tid = threadIdx.x;                         // pixel p
  __shared__ float sK[NN_];
  __shared__ int   sI[NN_];
  __shared__ float red[256];
  if (tid < NN_) { sI[tid] = ind[bl * NN_ + tid]; sK[tid] = Kscal[bl * NN_ + tid]; }
  __syncthreads();
  float lg[NN_];
  #pragma unroll
  for (int n = 0; n < NN_; ++n)
    lg[n] = Rc[sI[n] * P_ + tid] + Pc[(b * NN_ + n) * P_ + tid] + sK[n];
  float m = -3.4e38f;
  #pragma unroll
  for (int n = 0; n < NN_; ++n) m = fmaxf(m, lg[n]);
  red[tid] = m; __syncthreads();
  for (int s = 128; s > 0; s >>= 1) {
    if (tid < s) red[tid] = fmaxf(red[tid], red[tid + s]);
    __syncthreads();
  }
  m = red[0];
  __syncthreads();
  float ssum = 0.f;
  #pragma unroll
  for (int n = 0; n < NN_; ++n) { lg[n] = expf(lg[n] - m); ssum += lg[n]; }
  red[tid] = ssum; __syncthreads();
  for (int s = 128; s > 0; s >>= 1) {
    if (tid < s) red[tid] += red[tid + s];
    __syncthreads();
  }
  float inv = 1.0f / red[0];
  #pragma unroll
  for (int n = 0; n < NN_; ++n)
    attn[((size_t)bl * NN_ + n) * P_ + tid] = lg[n] * inv;
}

// gf[b,l,c] = sum_k attn[b,l,k] * Ft[b,k,c]  — M=1024, N=128, K=5120 per b.
// Block: 16 l x 128 c, 512 threads (thread = 1 l x 4 c). Coalesced Ft loads.
__global__ __launch_bounds__(512) void k_mm(const float* __restrict__ attn,
                                            const float* __restrict__ Ft,
                                            float* __restrict__ gf) {
  __shared__ float sW[16 * 260];                 // [l][k] padded, 16.6 KB
  int bid = blockIdx.x;                          // 256 blocks
  int b  = bid >> 6;
  int l0 = (bid & 63) << 4;
  int tid = threadIdx.x;
  int cg = tid & 31, c0 = cg << 2;
  int lg = tid >> 5;                             // 0..15
  float4 acc = make_float4(0.f, 0.f, 0.f, 0.f);
  const float* ftb = Ft + (size_t)b * K_ * C_ + c0;
  const float* arow = attn + ((size_t)b * L_ + l0) * K_;
  for (int k0 = 0; k0 < K_; k0 += 256) {
    __syncthreads();
    {
      int row = tid >> 5, kb = (tid & 31) << 3;  // 8 floats per thread
      const float* src = arow + (size_t)row * K_ + k0 + kb;
      float4 a0 = *(const float4*)(src);
      float4 a1 = *(const float4*)(src + 4);
      *(float4*)&sW[row * 260 + kb]     = a0;
      *(float4*)&sW[row * 260 + kb + 4] = a1;
    }
    __syncthreads();
    const float* fp = ftb + (size_t)k0 * C_;
    const float* wr = &sW[lg * 260];
    #pragma unroll 4
    for (int k = 0; k < 256; ++k) {
      float w = wr[k];
      float4 f = *(const float4*)(fp + (size_t)k * C_);
      acc.x += w * f.x; acc.y += w * f.y; acc.z += w * f.z; acc.w += w * f.w;
    }
  }
  *(float4*)&gf[((size_t)b * L_ + l0 + lg) * C_ + c0] = acc;
}

extern "C" void kernel_launch(void* const* d_in, const int* in_sizes, int n_in,
                              void* d_out, int out_size, void* d_ws, size_t ws_size,
                              hipStream_t stream) {
  const float* bbox  = (const float*)d_in[0];
  const float* locs  = (const float*)d_in[1];
  const float* feats = (const float*)d_in[2];
  const float* over  = (const float*)d_in[3];
  const float* rays  = (const float*)d_in[4];
  const float* w1    = (const float*)d_in[5];
  const float* b1    = (const float*)d_in[6];
  const float* w2    = (const float*)d_in[7];
  const float* b2    = (const float*)d_in[8];
  const float* fw    = (const float*)d_in[9];
  const float* fb    = (const float*)d_in[10];

  float* ws     = (float*)d_ws;
  int*   ind    = (int*)ws;
  float* Kscal  = ws + 81920;
  float* Rc     = ws + 163840;
  float* Pc     = ws + 256000;
  float* pano   = ws + 276480;
  float* ovmax  = ws + 317440;
  float* ovmean = ws + 321536;
  float* Ft     = ws + 325632;

  float* gf   = (float*)d_out;
  float* attn = gf + (B_ * L_ * C_);             // 20.97M floats

  k_pano<<<80, 256, 0, stream>>>(feats, pano);
  k_ov  <<<16, 256, 0, stream>>>(over, ovmax, ovmean);
  k_rc  <<<360, 256, 0, stream>>>(rays, w1, w2, fw, Rc);
  k_pc  <<<80, 256, 0, stream>>>(pano, w1, w2, fw, Pc);
  k_geo <<<320, 256, 0, stream>>>(bbox, locs, ovmax, ovmean, w1, w2, b1, b2, fw, fb,
                                  ind, Kscal);
  k_ft  <<<80, 256, 0, stream>>>(feats, Ft);
  k_soft<<<4096, 256, 0, stream>>>(Rc, Pc, Kscal, ind, attn);
  k_mm  <<<256, 512, 0, stream>>>(attn, Ft, gf);
}

// Round 8
// 311.126 us; speedup vs baseline: 4.2582x; 1.6882x over previous
//
#include <hip/hip_runtime.h>

#define B_  4
#define NN_ 20
#define C_  128
#define H_  8
#define W_  32
#define P_  256      // H*W
#define GS_ 32
#define L_  1024     // GS*GS
#define K_  5120     // NN*P

// ---------------- ws layout (float elements) ----------------
// ind   : int   [B*L*NN]   @ 0         (81920)
// Kscal : float [B*L*NN]   @ 81920     (81920)
// Rc    : float [360*P]    @ 163840    (92160)
// Pc    : float [B*NN*P]   @ 256000    (20480)
// pano  : float [B*NN*2*P] @ 276480    (40960)
// ovmax : float [B*L]      @ 317440    (4096)
// ovmean: float [B*L]      @ 321536    (4096)
// Ft    : float [B*K*C]    @ 325632    (2621440)
// part  : float [4*B*L*C]  @ 2947072   (2097152)  -> total 19.3 MB

__global__ __launch_bounds__(256) void k_pano(const float* __restrict__ feats,
                                              float* __restrict__ pano) {
  int t = blockIdx.x * 256 + threadIdx.x;       // B*NN*P = 20480
  int p = t & 255, bn = t >> 8;
  const float* src = feats + bn * C_ * P_ + p;
  float mx = -3.4e38f, sm = 0.f;
  #pragma unroll 8
  for (int c = 0; c < C_; ++c) { float v = src[c * P_]; mx = fmaxf(mx, v); sm += v; }
  pano[(bn * 2 + 0) * P_ + p] = mx;
  pano[(bn * 2 + 1) * P_ + p] = sm * (1.0f / 128.0f);
}

__global__ __launch_bounds__(256) void k_ov(const float* __restrict__ over,
                                            float* __restrict__ ovmax,
                                            float* __restrict__ ovmean) {
  int t = blockIdx.x * 256 + threadIdx.x;       // B*L = 4096
  int b = t >> 10, l = t & 1023;
  const float* src = over + b * C_ * L_ + l;
  float mx = -3.4e38f, sm = 0.f;
  #pragma unroll 8
  for (int c = 0; c < C_; ++c) { float v = src[c * L_]; mx = fmaxf(mx, v); sm += v; }
  ovmax[t] = mx; ovmean[t] = sm * (1.0f / 128.0f);
}

// Rays conv: Rc[a,p] = fw0*conv3(rays[a], w1[1..3]) + fw1*conv5(rays[a], w2[1..3])
__global__ __launch_bounds__(256) void k_rc(const float* __restrict__ rays,
                                            const float* __restrict__ w1,
                                            const float* __restrict__ w2,
                                            const float* __restrict__ fw,
                                            float* __restrict__ Rc) {
  __shared__ float s[3 * P_];
  int a = blockIdx.x, tid = threadIdx.x;
  #pragma unroll
  for (int c = 0; c < 3; ++c) s[c * P_ + tid] = rays[(a * 3 + c) * P_ + tid];
  __syncthreads();
  int y = tid >> 5, x = tid & 31;
  float acc1 = 0.f, acc2 = 0.f;
  #pragma unroll
  for (int c = 0; c < 3; ++c) {
    const float* sc  = s + c * P_;
    const float* w1c = w1 + (1 + c) * 9;
    const float* w2c = w2 + (1 + c) * 25;
    #pragma unroll
    for (int dy = 0; dy < 3; ++dy) { int yy = ((y + dy + 7) & 7) * 32;
      #pragma unroll
      for (int dx = 0; dx < 3; ++dx) { int xx = (x + dx + 31) & 31;
        acc1 += sc[yy + xx] * w1c[dy * 3 + dx]; } }
    #pragma unroll
    for (int dy = 0; dy < 5; ++dy) { int yy = ((y + dy + 6) & 7) * 32;
      #pragma unroll
      for (int dx = 0; dx < 5; ++dx) { int xx = (x + dx + 30) & 31;
        acc2 += sc[yy + xx] * w2c[dy * 5 + dx]; } }
  }
  Rc[a * P_ + tid] = fw[0] * acc1 + fw[1] * acc2;
}

// Pano conv: Pc[bn,p] = fw0*conv3(pano, w1[4..5]) + fw1*conv5(pano, w2[4..5])
__global__ __launch_bounds__(256) void k_pc(const float* __restrict__ pano,
                                            const float* __restrict__ w1,
                                            const float* __restrict__ w2,
                                            const float* __restrict__ fw,
                                            float* __restrict__ Pc) {
  __shared__ float s[2 * P_];
  int bn = blockIdx.x, tid = threadIdx.x;
  s[tid]      = pano[(bn * 2 + 0) * P_ + tid];
  s[P_ + tid] = pano[(bn * 2 + 1) * P_ + tid];
  __syncthreads();
  int y = tid >> 5, x = tid & 31;
  float acc1 = 0.f, acc2 = 0.f;
  #pragma unroll
  for (int c = 0; c < 2; ++c) {
    const float* sc  = s + c * P_;
    const float* w1c = w1 + (4 + c) * 9;
    const float* w2c = w2 + (4 + c) * 25;
    #pragma unroll
    for (int dy = 0; dy < 3; ++dy) { int yy = ((y + dy + 7) & 7) * 32;
      #pragma unroll
      for (int dx = 0; dx < 3; ++dx) { int xx = (x + dx + 31) & 31;
        acc1 += sc[yy + xx] * w1c[dy * 3 + dx]; } }
    #pragma unroll
    for (int dy = 0; dy < 5; ++dy) { int yy = ((y + dy + 6) & 7) * 32;
      #pragma unroll
      for (int dx = 0; dx < 5; ++dx) { int xx = (x + dx + 30) & 31;
        acc2 += sc[yy + xx] * w2c[dy * 5 + dx]; } }
  }
  Pc[bn * P_ + tid] = fw[0] * acc1 + fw[1] * acc2;
}

// Per-(b,l,n): ray index + scalar (constant-channel) logit term
__global__ __launch_bounds__(256) void k_geo(const float* __restrict__ bbox,
                                             const float* __restrict__ locs,
                                             const float* __restrict__ ovmax,
                                             const float* __restrict__ ovmean,
                                             const float* __restrict__ w1,
                                             const float* __restrict__ w2,
                                             const float* __restrict__ b1,
                                             const float* __restrict__ b2,
                                             const float* __restrict__ fw,
                                             const float* __restrict__ fb,
                                             int* __restrict__ ind,
                                             float* __restrict__ Kscal) {
  int t = blockIdx.x * 256 + threadIdx.x;       // B*L*NN = 81920
  int n = t % NN_;
  int r = t / NN_;                              // b*L + l
  int l = r & 1023, b = r >> 10;
  int i = l >> 5, j = l & 31;
  float y0 = bbox[b * 4 + 0], x0 = bbox[b * 4 + 1];
  float y1 = bbox[b * 4 + 2], x1 = bbox[b * 4 + 3];
  float gy = (i == 31) ? y1 : (y0 + ((y1 - y0) / 31.0f) * (float)i);  // linspace endpoint
  float gx = (j == 31) ? x1 : (x0 + ((x1 - x0) / 31.0f) * (float)j);
  float d0 = gy - locs[(b * NN_ + n) * 2 + 0];
  float d1 = gx - locs[(b * NN_ + n) * 2 + 1];
  float D  = sqrtf(d0 * d0 + d1 * d1 + 1e-12f);
  float th = atan2f(d1, d0);
  if (th < 0.f) th += 6.283185307179586f;
  float deg = th * 57.29577951308232f;
  int di = (int)rintf(deg);                     // round-half-even, matches jnp.round
  if (di >= 360) di -= 360;
  float s10 = 0, s16 = 0, s17 = 0;
  #pragma unroll
  for (int q = 0; q < 9; ++q) { s10 += w1[q]; s16 += w1[54 + q]; s17 += w1[63 + q]; }
  float s20 = 0, s26 = 0, s27 = 0;
  #pragma unroll
  for (int q = 0; q < 25; ++q) { s20 += w2[q]; s26 += w2[150 + q]; s27 += w2[175 + q]; }
  float om = ovmax[r], oa = ovmean[r];
  ind[t]   = di;
  Kscal[t] = fw[0] * (D * s10 + om * s16 + oa * s17 + b1[0])
           + fw[1] * (D * s20 + om * s26 + oa * s27 + b2[0]) + fb[0];
}

// Transpose feats [b,n,c,p] -> Ft [b, k=(n,p), c]  (c contiguous)
__global__ __launch_bounds__(256) void k_ft(const float* __restrict__ feats,
                                            float* __restrict__ Ft) {
  __shared__ float s[32 * 257];
  int bn = blockIdx.x;                           // b*NN + n
  int b = bn / NN_, n = bn % NN_;
  int tid = threadIdx.x;
  for (int c0 = 0; c0 < C_; c0 += 32) {
    __syncthreads();
    #pragma unroll 4
    for (int cc = 0; cc < 32; ++cc)
      s[cc * 257 + tid] = feats[(bn * C_ + c0 + cc) * P_ + tid];
    __syncthreads();
    int c = tid & 31, p8 = tid >> 5;
    #pragma unroll 4
    for (int pp = 0; pp < 32; ++pp) {
      int p = pp * 8 + p8;
      Ft[((size_t)b * K_ + n * P_ + p) * C_ + c0 + c] = s[c * 257 + p];
    }
  }
}

// Per grid cell: assemble logits, softmax over (n,p)=5120, write fp32 attn.
__global__ __launch_bounds__(256) void k_soft(const float* __restrict__ Rc,
                                              const float* __restrict__ Pc,
                                              const float* __restrict__ Kscal,
                                              const int* __restrict__ ind,
                                              float* __restrict__ attn) {
  int bl = blockIdx.x;                           // b*L + l
  int b = bl >> 10;
  int tid = threadIdx.x;                         // pixel p
  __shared__ float sK[NN_];
  __shared__ int   sI[NN_];
  __shared__ float red[256];
  if (tid < NN_) { sI[tid] = ind[bl * NN_ + tid]; sK[tid] = Kscal[bl * NN_ + tid]; }
  __syncthreads();
  float lg[NN_];
  #pragma unroll
  for (int n = 0; n < NN_; ++n)
    lg[n] = Rc[sI[n] * P_ + tid] + Pc[(b * NN_ + n) * P_ + tid] + sK[n];
  float m = -3.4e38f;
  #pragma unroll
  for (int n = 0; n < NN_; ++n) m = fmaxf(m, lg[n]);
  red[tid] = m; __syncthreads();
  for (int s = 128; s > 0; s >>= 1) {
    if (tid < s) red[tid] = fmaxf(red[tid], red[tid + s]);
    __syncthreads();
  }
  m = red[0];
  __syncthreads();
  float ssum = 0.f;
  #pragma unroll
  for (int n = 0; n < NN_; ++n) { lg[n] = expf(lg[n] - m); ssum += lg[n]; }
  red[tid] = ssum; __syncthreads();
  for (int s = 128; s > 0; s >>= 1) {
    if (tid < s) red[tid] += red[tid + s];
    __syncthreads();
  }
  float inv = 1.0f / red[0];
  #pragma unroll
  for (int n = 0; n < NN_; ++n)
    attn[((size_t)bl * NN_ + n) * P_ + tid] = lg[n] * inv;
}

// part[ks][b,l,c] = sum_{k in split ks} attn[b,l,k] * Ft[b,k,c]
// Grid 1024 = 4b x 64 ltiles x 4 ksplits; 256 thr; thread = 2 l x 4 c.
// LDS sW[k][l] (pad 18): float2 weight reads, 8 FMA per Ft float4 load.
__global__ __launch_bounds__(256) void k_mm(const float* __restrict__ attn,
                                            const float* __restrict__ Ft,
                                            float* __restrict__ part) {
  __shared__ float sW[256 * 18];                 // 18.4 KB
  int bid = blockIdx.x;
  int ks = bid & 3;
  int lt = (bid >> 2) & 63;
  int b  = bid >> 8;
  int l0 = lt << 4;
  int kbase = ks * (K_ / 4);                     // 1280
  int tid = threadIdx.x;
  int cg = tid & 31, c0 = cg << 2;
  int lg = tid >> 5;                             // 0..7 -> l = l0 + 2*lg + {0,1}
  float4 acc0 = make_float4(0.f, 0.f, 0.f, 0.f);
  float4 acc1 = make_float4(0.f, 0.f, 0.f, 0.f);
  const float* arow = attn + ((size_t)b * L_ + l0) * K_ + kbase;
  const float* ftb  = Ft + ((size_t)b * K_ + kbase) * C_ + c0;
  for (int kc0 = 0; kc0 < K_ / 4; kc0 += 256) {
    __syncthreads();
    #pragma unroll
    for (int r = 0; r < 16; ++r)
      sW[tid * 18 + r] = arow[(size_t)r * K_ + kc0 + tid];   // sW[k=tid][l=r]
    __syncthreads();
    const float* fp = ftb + (size_t)kc0 * C_;
    #pragma unroll 4
    for (int k = 0; k < 256; ++k) {
      float2 w = *(const float2*)&sW[k * 18 + 2 * lg];
      float4 f = *(const float4*)(fp + (size_t)k * C_);
      acc0.x += w.x * f.x; acc0.y += w.x * f.y; acc0.z += w.x * f.z; acc0.w += w.x * f.w;
      acc1.x += w.y * f.x; acc1.y += w.y * f.y; acc1.z += w.y * f.z; acc1.w += w.y * f.w;
    }
  }
  float* pt = part + (size_t)ks * (B_ * L_ * C_)
            + ((size_t)b * L_ + l0 + 2 * lg) * C_ + c0;
  *(float4*)pt        = acc0;
  *(float4*)(pt + C_) = acc1;
}

// gf = part0 + part1 + part2 + part3  (float4, 131072 groups)
__global__ __launch_bounds__(256) void k_red(const float* __restrict__ part,
                                             float* __restrict__ gf) {
  int t = blockIdx.x * 256 + threadIdx.x;        // 131072
  const float4* p = (const float4*)part;
  float4 a = p[t], b = p[t + 131072], c = p[t + 262144], d = p[t + 393216];
  float4 o;
  o.x = (a.x + b.x) + (c.x + d.x);
  o.y = (a.y + b.y) + (c.y + d.y);
  o.z = (a.z + b.z) + (c.z + d.z);
  o.w = (a.w + b.w) + (c.w + d.w);
  ((float4*)gf)[t] = o;
}

extern "C" void kernel_launch(void* const* d_in, const int* in_sizes, int n_in,
                              void* d_out, int out_size, void* d_ws, size_t ws_size,
                              hipStream_t stream) {
  const float* bbox  = (const float*)d_in[0];
  const float* locs  = (const float*)d_in[1];
  const float* feats = (const float*)d_in[2];
  const float* over  = (const float*)d_in[3];
  const float* rays  = (const float*)d_in[4];
  const float* w1    = (const float*)d_in[5];
  const float* b1    = (const float*)d_in[6];
  const float* w2    = (const float*)d_in[7];
  const float* b2    = (const float*)d_in[8];
  const float* fw    = (const float*)d_in[9];
  const float* fb    = (const float*)d_in[10];

  float* ws     = (float*)d_ws;
  int*   ind    = (int*)ws;
  float* Kscal  = ws + 81920;
  float* Rc     = ws + 163840;
  float* Pc     = ws + 256000;
  float* pano   = ws + 276480;
  float* ovmax  = ws + 317440;
  float* ovmean = ws + 321536;
  float* Ft     = ws + 325632;
  float* part   = ws + 2947072;

  float* gf   = (float*)d_out;
  float* attn = gf + (B_ * L_ * C_);             // 20.97M floats

  k_pano<<<80, 256, 0, stream>>>(feats, pano);
  k_ov  <<<16, 256, 0, stream>>>(over, ovmax, ovmean);
  k_rc  <<<360, 256, 0, stream>>>(rays, w1, w2, fw, Rc);
  k_pc  <<<80, 256, 0, stream>>>(pano, w1, w2, fw, Pc);
  k_geo <<<320, 256, 0, stream>>>(bbox, locs, ovmax, ovmean, w1, w2, b1, b2, fw, fb,
                                  ind, Kscal);
  k_ft  <<<80, 256, 0, stream>>>(feats, Ft);
  k_soft<<<4096, 256, 0, stream>>>(Rc, Pc, Kscal, ind, attn);
  k_mm  <<<1024, 256, 0, stream>>>(attn, Ft, part);
  k_red <<<512, 256, 0, stream>>>(part, gf);
}